// Round 6
// baseline (833.750 us; speedup 1.0000x reference)
//
#include <hip/hip_runtime.h>
#include <hip/hip_bf16.h>
#include <stdint.h>

#define DEV __device__ __forceinline__

typedef __attribute__((ext_vector_type(8))) short short8;
typedef __attribute__((ext_vector_type(8))) _Float16 half8;
typedef __attribute__((ext_vector_type(2))) __fp16 fp16x2;
typedef __attribute__((ext_vector_type(4))) float floatx4;
typedef __attribute__((ext_vector_type(16))) float floatx16;

DEV unsigned short f2bf(float f) {
  union { float f; uint32_t u; } v; v.f = f;
  uint32_t u = v.u;
  u += 0x7fffu + ((u >> 16) & 1u);   // RNE
  return (unsigned short)(u >> 16);
}
DEV unsigned short f2h(float f) {
  union { _Float16 h; unsigned short u; } c; c.h = (_Float16)f; return c.u;
}
DEV void async_cp16(const unsigned short* g, unsigned short* l) {
  __builtin_amdgcn_global_load_lds(
      (const __attribute__((address_space(1))) uint32_t*)g,
      (__attribute__((address_space(3))) uint32_t*)l, 16, 0, 0);
}

// ---------------------------------------------------------------------------
// cvt_x: fp32 -> bf16, coalesced. n multiple of 1024.
// ---------------------------------------------------------------------------
__global__ __launch_bounds__(256)
void cvt_x_kernel(const float* __restrict__ x, unsigned short* __restrict__ xb) {
  const size_t i = ((size_t)blockIdx.x * 256 + threadIdx.x) * 4;
  const float4 f = *(const float4*)(x + i);
  ushort4 w;
  w.x = f2bf(f.x); w.y = f2bf(f.y); w.z = f2bf(f.z); w.w = f2bf(f.w);
  *(ushort4*)(xb + i) = w;
}

// ---------------------------------------------------------------------------
// transpose_w: W[K][N] fp32 -> Wt[N][K] bf16. 64x64 LDS tiles.
// ---------------------------------------------------------------------------
__global__ __launch_bounds__(256)
void transpose_w_kernel(const float* __restrict__ W, unsigned short* __restrict__ Wt,
                        int K, int N) {
  __shared__ float tile[64][65];
  const int k0 = blockIdx.y * 64, n0 = blockIdx.x * 64;
  const int tr = threadIdx.x >> 4;
  const int tc = (threadIdx.x & 15) * 4;
#pragma unroll
  for (int it = 0; it < 4; ++it) {
    const int k = tr + it * 16;
    const float4 f = *(const float4*)(W + (size_t)(k0 + k) * N + n0 + tc);
    tile[k][tc + 0] = f.x; tile[k][tc + 1] = f.y;
    tile[k][tc + 2] = f.z; tile[k][tc + 3] = f.w;
  }
  __syncthreads();
#pragma unroll
  for (int it = 0; it < 4; ++it) {
    const int n = tr + it * 16;
    ushort4 w;
    w.x = f2bf(tile[tc + 0][n]); w.y = f2bf(tile[tc + 1][n]);
    w.z = f2bf(tile[tc + 2][n]); w.w = f2bf(tile[tc + 3][n]);
    *(ushort4*)(Wt + (size_t)(n0 + n) * K + k0 + tc) = w;
  }
}

// ---------------------------------------------------------------------------
// 256xBN 8-phase bf16 GEMM, BK=32 (64KB/48KB LDS -> 2 blocks/CU residency).
// C = A[M,K] * Bt[N,K]^T + bias.  BN in {256,128}, 512 thr = 8 waves (2Mx4N).
// r0/r3/r5 showed all 1-block/CU schedules pin at ~100us & MfmaUtil 20%:
// with one block per CU every barrier stall idles the CU. BK=32 halves LDS
// so TWO blocks co-reside; cross-block TLP fills the barrier stalls.
//
// LDS: L[2][ A[256][32] | B[BN][32] ]. Swizzle for 64B rows: 16B slot
// quad ^ ((row>>2)&3)  (=(l16>>2) for all our reads) -> 8-slot spread,
// 2-way residual (free per m136). Linear DMA dest + inverse-swizzled source.
//
// Stage schedule per tile t (buf P = t&1), 2 phases:
//   ph1 (m-half 0, RB): stage A(t+1)->P^1  [P^1 A free since t-1 ph2 bar]
//   ph2 (m-half 1    ): stage B(t+2)->P    [P B free since ph1 bar], then
//        VMW(NB): leaves only B(t+2) in flight => tile t+1 fully resident.
// LGK0 after barrier (r3/r4-proven: explicit drain beats compiler's WAR
// placement before the stage issue).
// ---------------------------------------------------------------------------
#define BAR asm volatile("s_barrier" ::: "memory")
#define LGK0 asm volatile("s_waitcnt lgkmcnt(0)" ::: "memory")
#define VMW(N) asm volatile("s_waitcnt vmcnt(" #N ")" ::: "memory")
#define NOW (void)0
#define NOSTG (void)0

template <int EPI, int BN>
__global__ __launch_bounds__(512, 4)
void gemm256_kernel(const unsigned short* __restrict__ A,
                    const unsigned short* __restrict__ Bt,
                    const float* __restrict__ bias, int M, int N, int K,
                    int nbx,
                    unsigned short* __restrict__ qws,
                    unsigned short* __restrict__ kws,
                    unsigned short* __restrict__ vws,
                    float* __restrict__ out) {
  (void)M;
  constexpr int NF = BN / 64;  // per-wave n-frags; B rows = BN
  __shared__ __align__(16) unsigned short L[2][8192 + NF * 2048];
  const int tid = threadIdx.x;
  const int wid = tid >> 6, lane = tid & 63;
  const int quad = lane >> 4, l16 = lane & 15;
  const int wm = wid >> 2, wn = wid & 3;

  // T1: XCD-aware swizzle (gridDim.x % 8 == 0 at both call sites -> bijective).
  const int nwg = (int)gridDim.x;
  const int bid = (int)blockIdx.x;
  const int swz = (bid & 7) * (nwg >> 3) + (bid >> 3);
  const int bx = swz % nbx, by = swz / nbx;
  const int rowA0 = by * 256, colB0 = bx * BN;

  // Staging: thread tid covers 16B chunk (row = tid>>2, slot = tid&3) of each
  // 128-row region. Pre-swizzled source: slot s of row r holds logical
  // k-slot s ^ ((r>>2)&3); (r>>2)&3 == (tid>>4)&3 for every region base
  // (multiples of 128 rows), so one ksrc serves all regions.
  const int srow = tid >> 2;                                   // 0..127
  const int ksrc = (((tid & 3) ^ ((tid >> 4) & 3)) << 3);      // shorts
  const unsigned short* pA0 = A + (size_t)(rowA0 + srow) * K + ksrc;
  const unsigned short* pA1 = A + (size_t)(rowA0 + 128 + srow) * K + ksrc;
  const unsigned short* pB0 = Bt + (size_t)(colB0 + srow) * K + ksrc;
  const unsigned short* pB1 =
      (BN == 256) ? Bt + (size_t)(colB0 + 128 + srow) * K + ksrc : pB0;

#define STG_A(P, T) do { async_cp16(pA0 + (T)*32, &L[P][0    + wid*512]); \
                         async_cp16(pA1 + (T)*32, &L[P][4096 + wid*512]); } while (0)
#define STG_B(P, T) do { \
    async_cp16(pB0 + (T)*32, &L[P][8192 + wid*512]); \
    if constexpr (BN == 256) { \
      async_cp16(pB1 + (T)*32, &L[P][12288 + wid*512]); } } while (0)
#define VMW_STEADY do { if constexpr (BN == 256) { VMW(2); } else { VMW(1); } } while (0)

  floatx4 acc[8][NF];
#pragma unroll
  for (int i = 0; i < 8; ++i)
#pragma unroll
    for (int j = 0; j < NF; ++j) acc[i][j] = (floatx4){0.f, 0.f, 0.f, 0.f};
  short8 bfrag[NF];

  // Reads: row_*32 + rslot; rslot = (quad ^ (l16>>2))*8 shorts (lane-const).
  const int rslot = (quad ^ (l16 >> 2)) << 3;

  // Prologue: tile0 + B(t1); VMW leaves only B(t1) in flight.
  STG_A(0, 0); STG_B(0, 0);
  STG_B(1, 1);
  VMW_STEADY;
  BAR;

#define PHASE(PAR, QM, RB, STG, W)                                            \
  {                                                                           \
    short8 a_[4];                                                             \
    _Pragma("unroll") for (int m_ = 0; m_ < 4; ++m_) {                        \
      const int row_ = wm * 128 + ((QM)*4 + m_) * 16 + l16;                   \
      a_[m_] = *(const short8*)&L[PAR][row_ * 32 + rslot];                    \
    }                                                                         \
    if (RB) {                                                                 \
      _Pragma("unroll") for (int n_ = 0; n_ < NF; ++n_) {                     \
        const int row_ = wn * (BN / 4) + n_ * 16 + l16;                       \
        bfrag[n_] = *(const short8*)&L[PAR][8192 + row_ * 32 + rslot];        \
      }                                                                       \
    }                                                                         \
    STG;                                                                      \
    BAR;                                                                      \
    LGK0;                                                                     \
    __builtin_amdgcn_s_setprio(1);                                            \
    _Pragma("unroll") for (int m_ = 0; m_ < 4; ++m_)                          \
      _Pragma("unroll") for (int n_ = 0; n_ < NF; ++n_)                       \
        acc[(QM)*4 + m_][n_] = __builtin_amdgcn_mfma_f32_16x16x32_bf16(       \
            a_[m_], bfrag[n_], acc[(QM)*4 + m_][n_], 0, 0, 0);                \
    __builtin_amdgcn_s_setprio(0);                                            \
    W;                                                                        \
    BAR;                                                                      \
  }

#define KTILE(PAR, S1, S2, W2) \
  PHASE(PAR, 0, 1, S1, NOW)    \
  PHASE(PAR, 1, 0, S2, W2)

  // K=1024 -> 32 tiles. Steady: tiles 0..29; tail 30 (drain), 31 (compute).
  for (int t0 = 0; t0 < 30; t0 += 2) {
    KTILE(0, STG_A(1, t0 + 1), STG_B(0, t0 + 2), VMW_STEADY)
    KTILE(1, STG_A(0, t0 + 2), STG_B(1, t0 + 3), VMW_STEADY)
  }
  KTILE(0, STG_A(1, 31), NOSTG, VMW(0))
  KTILE(1, NOSTG, NOSTG, NOW)

#undef KTILE
#undef PHASE
#undef STG_A
#undef STG_B
#undef VMW_STEADY

  // Epilogue. C/D: row = quad*4 + r, col = l16 (dtype-independent).
#pragma unroll
  for (int mi = 0; mi < 8; ++mi) {
#pragma unroll
    for (int ni = 0; ni < NF; ++ni) {
      const int row0 = rowA0 + wm * 128 + mi * 16 + quad * 4;
      const int col = colB0 + wn * (BN / 4) + ni * 16 + l16;
      const float bv = bias[col];
#pragma unroll
      for (int r = 0; r < 4; ++r) {
        const float v = acc[mi][ni][r] + bv;
        const int R = row0 + r;
        if constexpr (EPI == 0) {
          const int b = R >> 11, t = R & 2047;
          const int which = col >> 10, c = col & 1023;
          const int h = c >> 6, dd = c & 63;
          const size_t bh = (size_t)(b * 16 + h);
          if (which == 0)
            qws[(bh * 2048 + t) * 64 + dd] = f2bf(v * 0.125f);  // Q, scale folded
          else if (which == 1)
            kws[(bh * 2048 + t) * 64 + dd] = f2bf(v);           // K [bh][t][d]
          else
            vws[(bh * 64 + dd) * 2048 + t] = f2h(v);            // V^T f16 [bh][d][t]
        } else {
          out[(size_t)R * N + col] = v;
        }
      }
    }
  }
}

// ---------------------------------------------------------------------------
// MFMA flash attention (unchanged). Grid (64 bh, 16 qtiles), block 256.
// ---------------------------------------------------------------------------
__global__ __launch_bounds__(256, 2)
void attn_mfma_kernel(const unsigned short* __restrict__ qws,
                      const unsigned short* __restrict__ kws,
                      const unsigned short* __restrict__ vws,
                      unsigned short* __restrict__ yws) {
  constexpr int T = 2048, D = 64;
  __shared__ __align__(16) unsigned short Ks[128 * 72];
  __shared__ __align__(16) unsigned short Vs[64 * 136];
  const int tid = threadIdx.x;
  const int wid = tid >> 6, lane = tid & 63;
  const int hf = lane >> 5, l32 = lane & 31;
  const int bh = blockIdx.x;
  const int qt = 15 - (int)blockIdx.y;
  const int qbase = qt * 128;
  const unsigned short* Qp = qws + (size_t)bh * T * D;
  const unsigned short* Kp = kws + (size_t)bh * T * D;
  const unsigned short* Vp = vws + (size_t)bh * D * T;

  const int q = qbase + wid * 32 + l32;
  short8 qf[4];
#pragma unroll
  for (int s = 0; s < 4; ++s)
    qf[s] = *(const short8*)(Qp + (size_t)q * D + s * 16 + hf * 8);

  floatx16 Oacc[2];
#pragma unroll
  for (int mt2 = 0; mt2 < 2; ++mt2)
#pragma unroll
    for (int i = 0; i < 16; ++i) Oacc[mt2][i] = 0.f;
  float mrun = -1e30f, lrun = 0.f;

  for (int kt = 0; kt <= qt; ++kt) {
    const int kb = kt * 128;
    __syncthreads();
#pragma unroll
    for (int it = 0; it < 4; ++it) {
      const int e = it * 256 + tid;
      {
        const int row = e >> 3, c = (e & 7) * 8;
        *(short8*)&Ks[row * 72 + c] =
            *(const short8*)(Kp + (size_t)(kb + row) * D + c);
      }
      {
        const int row = e >> 4, c = (e & 15) * 8;
        *(short8*)&Vs[row * 136 + c] =
            *(const short8*)(Vp + (size_t)row * T + kb + c);
      }
    }
    __syncthreads();

    const bool diag = (kt == qt);
    const int mtmax = diag ? (wid + 1) : 4;

    floatx16 S[4];
#pragma unroll
    for (int mt = 0; mt < 4; ++mt)
      if (mt < mtmax)
#pragma unroll
        for (int i = 0; i < 16; ++i) S[mt][i] = 0.f;

#pragma unroll
    for (int s = 0; s < 4; ++s) {
#pragma unroll
      for (int mt = 0; mt < 4; ++mt)
        if (mt < mtmax) {
          const short8 kf =
              *(const short8*)&Ks[(mt * 32 + l32) * 72 + s * 16 + hf * 8];
          S[mt] = __builtin_amdgcn_mfma_f32_32x32x16_bf16(kf, qf[s], S[mt], 0, 0, 0);
        }
    }

    if (diag) {
#pragma unroll
      for (int mt = 0; mt < 4; ++mt)
        if (mt == wid) {
#pragma unroll
          for (int r = 0; r < 16; ++r) {
            const int intra = (r & 3) + 8 * (r >> 2) + 4 * hf;
            if (intra > l32) S[mt][r] = -1e30f;
          }
        }
    }

    float tmax = -1e30f;
#pragma unroll
    for (int mt = 0; mt < 4; ++mt)
      if (mt < mtmax)
#pragma unroll
        for (int r = 0; r < 16; ++r) tmax = fmaxf(tmax, S[mt][r]);
    tmax = fmaxf(tmax, __shfl_xor(tmax, 32, 64));
    const float mn = fmaxf(mrun, tmax);
    const float alpha = __expf(mrun - mn);
    mrun = mn;

    float tsum = 0.f;
    uint32_t pk[4][8];
#pragma unroll
    for (int mt = 0; mt < 4; ++mt)
      if (mt < mtmax)
#pragma unroll
        for (int t = 0; t < 8; ++t) {
          const float pa = __expf(S[mt][2 * t] - mn);
          const float pb = __expf(S[mt][2 * t + 1] - mn);
          tsum += pa + pb;
          union { fp16x2 h; uint32_t u; } cv;
          cv.h = __builtin_amdgcn_cvt_pkrtz(pa, pb);
          pk[mt][t] = cv.u;
        }
    tsum += __shfl_xor(tsum, 32, 64);
    lrun = lrun * alpha + tsum;
#pragma unroll
    for (int mt2 = 0; mt2 < 2; ++mt2)
#pragma unroll
      for (int i = 0; i < 16; ++i) Oacc[mt2][i] *= alpha;

    const int smax = 2 * mtmax;
#pragma unroll
    for (int s = 0; s < 8; ++s)
      if (s < smax) {
        const int mt = s >> 1;
        const int bo = 4 * (s & 1);
        const uint32_t own0 = hf ? pk[mt][bo + 2] : pk[mt][bo];
        const uint32_t own1 = hf ? pk[mt][bo + 3] : pk[mt][bo + 1];
        const uint32_t sendA = hf ? pk[mt][bo] : pk[mt][bo + 2];
        const uint32_t sendB = hf ? pk[mt][bo + 1] : pk[mt][bo + 3];
        const uint32_t recvA = (uint32_t)__shfl_xor((int)sendA, 32, 64);
        const uint32_t recvB = (uint32_t)__shfl_xor((int)sendB, 32, 64);
        union { uint32_t u[4]; half8 h; } bb;
        bb.u[0] = hf ? recvA : own0;
        bb.u[1] = hf ? recvB : own1;
        bb.u[2] = hf ? own0 : recvA;
        bb.u[3] = hf ? own1 : recvB;
#pragma unroll
        for (int mt2 = 0; mt2 < 2; ++mt2) {
          const half8 vf =
              *(const half8*)&Vs[(mt2 * 32 + l32) * 136 + s * 16 + hf * 8];
          Oacc[mt2] = __builtin_amdgcn_mfma_f32_32x32x16_f16(vf, bb.h, Oacc[mt2], 0, 0, 0);
        }
      }
  }

  const float invl = 1.0f / lrun;
  const int b_ = bh >> 4, h_ = bh & 15;
  unsigned short* yrow = yws + ((size_t)(b_ * 2048 + q)) * 1024 + h_ * 64;
#pragma unroll
  for (int mt2 = 0; mt2 < 2; ++mt2)
#pragma unroll
    for (int t = 0; t < 8; ++t) {
      const int d0 = mt2 * 32 + 2 * (t & 1) + 8 * (t >> 1) + 4 * hf;
      const uint32_t ua = f2bf(Oacc[mt2][2 * t] * invl);
      const uint32_t ub = f2bf(Oacc[mt2][2 * t + 1] * invl);
      *(uint32_t*)&yrow[d0] = ua | (ub << 16);
    }
}

// ---------------------------------------------------------------------------
extern "C" void kernel_launch(void* const* d_in, const int* in_sizes, int n_in,
                              void* d_out, int out_size, void* d_ws, size_t ws_size,
                              hipStream_t stream) {
  (void)in_sizes; (void)n_in; (void)out_size;
  const float* x = (const float*)d_in[0];
  const float* attn_w = (const float*)d_in[1];
  const float* attn_b = (const float*)d_in[2];
  const float* proj_w = (const float*)d_in[3];
  const float* proj_b = (const float*)d_in[4];
  float* out = (float*)d_out;

  const size_t NQ = 8388608;  // 4*16*2048*64 == 8192*1024
  unsigned short* qws = (unsigned short*)d_ws;
  unsigned short* kws = qws + NQ;
  unsigned short* vws = kws + NQ;
  unsigned short* yws = vws + NQ;
  unsigned short* xb  = yws + NQ;
  unsigned short* wta = xb + NQ;               // 3072*1024
  unsigned short* wtp = wta + 3072 * 1024;     // 1024*1024
  if (ws_size < (5 * NQ + 4 * 1024 * 1024) * sizeof(unsigned short)) return;

  cvt_x_kernel<<<dim3(8192), dim3(256), 0, stream>>>(x, xb);
  transpose_w_kernel<<<dim3(48, 16), dim3(256), 0, stream>>>(attn_w, wta, 1024, 3072);
  transpose_w_kernel<<<dim3(16, 16), dim3(256), 0, stream>>>(proj_w, wtp, 1024, 1024);

  // QKV: M=8192, N=3072 (BN=256) -> 32x12 = 384 blocks; 2 blocks/CU resident.
  gemm256_kernel<0, 256><<<dim3(384), dim3(512), 0, stream>>>(
      xb, wta, attn_b, 8192, 3072, 1024, 12, qws, kws, vws, nullptr);
  attn_mfma_kernel<<<dim3(64, 16), dim3(256), 0, stream>>>(qws, kws, vws, yws);
  // Proj: M=8192, N=1024 (BN=128) -> 32x8 = 256 blocks (48KB LDS).
  gemm256_kernel<1, 128><<<dim3(256), dim3(512), 0, stream>>>(
      yws, wtp, proj_b, 8192, 1024, 1024, 8, nullptr, nullptr, nullptr, out);
}

// Round 7
// 279.280 us; speedup vs baseline: 2.9854x; 2.9854x over previous
//
#include <hip/hip_runtime.h>
#include <hip/hip_bf16.h>
#include <stdint.h>

#define DEV __device__ __forceinline__

typedef __attribute__((ext_vector_type(8))) short short8;
typedef __attribute__((ext_vector_type(8))) _Float16 half8;
typedef __attribute__((ext_vector_type(2))) __fp16 fp16x2;
typedef __attribute__((ext_vector_type(4))) float floatx4;
typedef __attribute__((ext_vector_type(16))) float floatx16;

DEV unsigned short f2bf(float f) {
  union { float f; uint32_t u; } v; v.f = f;
  uint32_t u = v.u;
  u += 0x7fffu + ((u >> 16) & 1u);   // RNE
  return (unsigned short)(u >> 16);
}
DEV unsigned short f2h(float f) {
  union { _Float16 h; unsigned short u; } c; c.h = (_Float16)f; return c.u;
}
DEV void async_cp16(const unsigned short* g, unsigned short* l) {
  __builtin_amdgcn_global_load_lds(
      (const __attribute__((address_space(1))) uint32_t*)g,
      (__attribute__((address_space(3))) uint32_t*)l, 16, 0, 0);
}

// ---------------------------------------------------------------------------
// cvt_x: fp32 -> bf16, coalesced.
// ---------------------------------------------------------------------------
__global__ __launch_bounds__(256)
void cvt_x_kernel(const float* __restrict__ x, unsigned short* __restrict__ xb) {
  const size_t i = ((size_t)blockIdx.x * 256 + threadIdx.x) * 4;
  const float4 f = *(const float4*)(x + i);
  ushort4 w;
  w.x = f2bf(f.x); w.y = f2bf(f.y); w.z = f2bf(f.z); w.w = f2bf(f.w);
  *(ushort4*)(xb + i) = w;
}

// ---------------------------------------------------------------------------
// transpose_w: W[K][N] fp32 -> Wt[N][K] bf16. 64x64 LDS tiles.
// ---------------------------------------------------------------------------
__global__ __launch_bounds__(256)
void transpose_w_kernel(const float* __restrict__ W, unsigned short* __restrict__ Wt,
                        int K, int N) {
  __shared__ float tile[64][65];
  const int k0 = blockIdx.y * 64, n0 = blockIdx.x * 64;
  const int tr = threadIdx.x >> 4;
  const int tc = (threadIdx.x & 15) * 4;
#pragma unroll
  for (int it = 0; it < 4; ++it) {
    const int k = tr + it * 16;
    const float4 f = *(const float4*)(W + (size_t)(k0 + k) * N + n0 + tc);
    tile[k][tc + 0] = f.x; tile[k][tc + 1] = f.y;
    tile[k][tc + 2] = f.z; tile[k][tc + 3] = f.w;
  }
  __syncthreads();
#pragma unroll
  for (int it = 0; it < 4; ++it) {
    const int n = tr + it * 16;
    ushort4 w;
    w.x = f2bf(tile[tc + 0][n]); w.y = f2bf(tile[tc + 1][n]);
    w.z = f2bf(tile[tc + 2][n]); w.w = f2bf(tile[tc + 3][n]);
    *(ushort4*)(Wt + (size_t)(n0 + n) * K + k0 + tc) = w;
  }
}

// ---------------------------------------------------------------------------
// 256xBN GEMM, BK=64, TWO 32-MFMA phases per K-tile (32 phases total).
// r0-r5 evidence: every 64-phase schedule = ~100us regardless of content
// (gemm1 at 1/3 FLOPs = same 100us) -> per-phase fixed cost dominates.
// This halves phase count by doubling MFMA per phase.
//
// LDS per buffer: K-half regions A_K0|A_K1|B_K0|B_K1, 64B rows (32 shorts).
// Swizzle (r6-verified algebra): physical 16B slot s of row r holds logical
// k-chunk s ^ ((r>>2)&3); read slot = quad ^ (l16>>2). Linear DMA dest +
// pre-swizzled global source.
//
// Phase (tile t, buf P=t&1): ph0 reads K0 regions, ph1 reads K1 regions.
//   ph0 stages K1(t+1)->P^1  [K1(P^1) last read ph1(t-1), freed by barrier]
//   ph1 stages K0(t+2)->P    [K0(P) last read ph0(t), freed by barrier]
// Every region freed exactly one barrier before restaging. Distance-3 for
// all loads; steady vmcnt(8|6) keeps newest 2 phases in flight; LGK0 after
// barrier (r3/r4: explicit drain beats compiler WAR placement).
// launch_bounds (512,2): r6 showed (512,4) clamps regs to 64 -> acc spills
// to scratch (1.7GB writes, 3% MfmaUtil). Never bound below acc size.
// ---------------------------------------------------------------------------
#define BAR asm volatile("s_barrier" ::: "memory")
#define LGK0 asm volatile("s_waitcnt lgkmcnt(0)" ::: "memory")
#define VMW(N) asm volatile("s_waitcnt vmcnt(" #N ")" ::: "memory")
#define NOW (void)0
#define NOSTG (void)0

template <int EPI, int BN>
__global__ __launch_bounds__(512, 2)
void gemm256_kernel(const unsigned short* __restrict__ A,
                    const unsigned short* __restrict__ Bt,
                    const float* __restrict__ bias, int M, int N, int K,
                    int nbx,
                    unsigned short* __restrict__ qws,
                    unsigned short* __restrict__ kws,
                    unsigned short* __restrict__ vws,
                    float* __restrict__ out) {
  (void)M;
  constexpr int NF = BN / 64;          // per-wave n-frags
  constexpr int BREG = NF * 2048;      // B K-half region size (shorts)
  __shared__ __align__(16) unsigned short L[2][16384 + 2 * BREG];
  const int tid = threadIdx.x;
  const int wid = tid >> 6, lane = tid & 63;
  const int quad = lane >> 4, l16 = lane & 15;
  const int wm = wid >> 2, wn = wid & 3;

  // T1: XCD-aware swizzle (gridDim.x % 8 == 0 -> bijective).
  const int nwg = (int)gridDim.x;
  const int bid = (int)blockIdx.x;
  const int swz = (bid & 7) * (nwg >> 3) + (bid >> 3);
  const int bx = swz % nbx, by = swz / nbx;
  const int rowA0 = by * 256, colB0 = bx * BN;

  // Staging: thread tid covers (row = tid>>2 in 0..127, 16B slot = tid&3) of
  // a 128-row region-half. Pre-swizzled source k-chunk = (tid&3)^((tid>>4)&3).
  const int srow = tid >> 2;
  const int ksrc = (((tid & 3) ^ ((tid >> 4) & 3)) << 3);      // shorts
  const unsigned short* gA  = A + (size_t)(rowA0 + srow) * K + ksrc;
  const unsigned short* gA2 = A + (size_t)(rowA0 + 128 + srow) * K + ksrc;
  const unsigned short* gB  = Bt + (size_t)(colB0 + srow) * K + ksrc;
  const unsigned short* gB2 =
      (BN == 256) ? Bt + (size_t)(colB0 + 128 + srow) * K + ksrc : gB;

  // Region bases (shorts): A_K0=0, A_K1=8192, B_K0=16384, B_K1=16384+BREG.
#define STG_AK(P, T, H) do { \
    async_cp16(gA  + (T)*64 + (H)*32, &L[P][(H)*8192 + wid*512]); \
    async_cp16(gA2 + (T)*64 + (H)*32, &L[P][(H)*8192 + 4096 + wid*512]); } while (0)
#define STG_BK(P, T, H) do { \
    async_cp16(gB  + (T)*64 + (H)*32, &L[P][16384 + (H)*BREG + wid*512]); \
    if constexpr (BN == 256) { \
      async_cp16(gB2 + (T)*64 + (H)*32, &L[P][16384 + (H)*BREG + 4096 + wid*512]); } \
  } while (0)
#define STG_K0(P, T) do { STG_AK(P, T, 0); STG_BK(P, T, 0); } while (0)
#define STG_K1(P, T) do { STG_AK(P, T, 1); STG_BK(P, T, 1); } while (0)
#define VMW_S do { if constexpr (BN == 256) { VMW(8); } else { VMW(6); } } while (0)
#define VMW_H do { if constexpr (BN == 256) { VMW(4); } else { VMW(3); } } while (0)

  floatx4 acc[8][NF];
#pragma unroll
  for (int i = 0; i < 8; ++i)
#pragma unroll
    for (int j = 0; j < NF; ++j) acc[i][j] = (floatx4){0.f, 0.f, 0.f, 0.f};

  // Read slot within 64B row (lane-constant, shorts).
  const int rslot = (quad ^ (l16 >> 2)) << 3;

  // Prologue: K0(t0), K1(t0), K0(t1); wait leaves newest 2 groups in flight.
  STG_K0(0, 0);
  STG_K1(0, 0);
  STG_K0(1, 1);
  VMW_S;
  BAR;

#define PHASE(PAR, KS, STG, W)                                                \
  {                                                                           \
    short8 a_[8];                                                             \
    _Pragma("unroll") for (int m_ = 0; m_ < 8; ++m_) {                        \
      const int row_ = wm * 128 + m_ * 16 + l16;                              \
      a_[m_] = *(const short8*)&L[PAR][(KS)*8192 + row_ * 32 + rslot];        \
    }                                                                         \
    short8 bfr_[NF];                                                          \
    _Pragma("unroll") for (int n_ = 0; n_ < NF; ++n_) {                       \
      const int row_ = wn * (BN / 4) + n_ * 16 + l16;                         \
      bfr_[n_] = *(const short8*)&L[PAR][16384 + (KS)*BREG + row_ * 32 + rslot]; \
    }                                                                         \
    STG;                                                                      \
    BAR;                                                                      \
    LGK0;                                                                     \
    __builtin_amdgcn_s_setprio(1);                                            \
    _Pragma("unroll") for (int m_ = 0; m_ < 8; ++m_)                          \
      _Pragma("unroll") for (int n_ = 0; n_ < NF; ++n_)                       \
        acc[m_][n_] = __builtin_amdgcn_mfma_f32_16x16x32_bf16(                \
            a_[m_], bfr_[n_], acc[m_][n_], 0, 0, 0);                          \
    __builtin_amdgcn_s_setprio(0);                                            \
    W;                                                                        \
    BAR;                                                                      \
  }

  // Steady: tiles 0..13 (K=1024 -> 16 tiles).
  for (int t0 = 0; t0 < 14; t0 += 2) {
    PHASE(0, 0, STG_K1(1, t0 + 1), VMW_S)   // tile t0   ph0
    PHASE(0, 1, STG_K0(0, t0 + 2), VMW_S)   // tile t0   ph1
    PHASE(1, 0, STG_K1(0, t0 + 2), VMW_S)   // tile t0+1 ph0
    PHASE(1, 1, STG_K0(1, t0 + 3), VMW_S)   // tile t0+1 ph1
  }
  // Tile 14: ph0 stages K1(t15) (last stage), ph1 half-drain.
  PHASE(0, 0, STG_K1(1, 15), VMW_S)
  PHASE(0, 1, NOSTG, VMW_H)
  // Tile 15: full drain, then pure compute.
  PHASE(1, 0, NOSTG, VMW(0))
  PHASE(1, 1, NOSTG, NOW)

#undef PHASE
#undef STG_AK
#undef STG_BK
#undef STG_K0
#undef STG_K1
#undef VMW_S
#undef VMW_H

  // Epilogue. C/D: row = quad*4 + r, col = l16 (dtype-independent).
#pragma unroll
  for (int mi = 0; mi < 8; ++mi) {
#pragma unroll
    for (int ni = 0; ni < NF; ++ni) {
      const int row0 = rowA0 + wm * 128 + mi * 16 + quad * 4;
      const int col = colB0 + wn * (BN / 4) + ni * 16 + l16;
      const float bv = bias[col];
#pragma unroll
      for (int r = 0; r < 4; ++r) {
        const float v = acc[mi][ni][r] + bv;
        const int R = row0 + r;
        if constexpr (EPI == 0) {
          const int b = R >> 11, t = R & 2047;
          const int which = col >> 10, c = col & 1023;
          const int h = c >> 6, dd = c & 63;
          const size_t bh = (size_t)(b * 16 + h);
          if (which == 0)
            qws[(bh * 2048 + t) * 64 + dd] = f2bf(v * 0.125f);  // Q, scale folded
          else if (which == 1)
            kws[(bh * 2048 + t) * 64 + dd] = f2bf(v);           // K [bh][t][d]
          else
            vws[(bh * 64 + dd) * 2048 + t] = f2h(v);            // V^T f16 [bh][d][t]
        } else {
          out[(size_t)R * N + col] = v;
        }
      }
    }
  }
}

// ---------------------------------------------------------------------------
// MFMA flash attention (unchanged). Grid (64 bh, 16 qtiles), block 256.
// ---------------------------------------------------------------------------
__global__ __launch_bounds__(256, 2)
void attn_mfma_kernel(const unsigned short* __restrict__ qws,
                      const unsigned short* __restrict__ kws,
                      const unsigned short* __restrict__ vws,
                      unsigned short* __restrict__ yws) {
  constexpr int T = 2048, D = 64;
  __shared__ __align__(16) unsigned short Ks[128 * 72];
  __shared__ __align__(16) unsigned short Vs[64 * 136];
  const int tid = threadIdx.x;
  const int wid = tid >> 6, lane = tid & 63;
  const int hf = lane >> 5, l32 = lane & 31;
  const int bh = blockIdx.x;
  const int qt = 15 - (int)blockIdx.y;
  const int qbase = qt * 128;
  const unsigned short* Qp = qws + (size_t)bh * T * D;
  const unsigned short* Kp = kws + (size_t)bh * T * D;
  const unsigned short* Vp = vws + (size_t)bh * D * T;

  const int q = qbase + wid * 32 + l32;
  short8 qf[4];
#pragma unroll
  for (int s = 0; s < 4; ++s)
    qf[s] = *(const short8*)(Qp + (size_t)q * D + s * 16 + hf * 8);

  floatx16 Oacc[2];
#pragma unroll
  for (int mt2 = 0; mt2 < 2; ++mt2)
#pragma unroll
    for (int i = 0; i < 16; ++i) Oacc[mt2][i] = 0.f;
  float mrun = -1e30f, lrun = 0.f;

  for (int kt = 0; kt <= qt; ++kt) {
    const int kb = kt * 128;
    __syncthreads();
#pragma unroll
    for (int it = 0; it < 4; ++it) {
      const int e = it * 256 + tid;
      {
        const int row = e >> 3, c = (e & 7) * 8;
        *(short8*)&Ks[row * 72 + c] =
            *(const short8*)(Kp + (size_t)(kb + row) * D + c);
      }
      {
        const int row = e >> 4, c = (e & 15) * 8;
        *(short8*)&Vs[row * 136 + c] =
            *(const short8*)(Vp + (size_t)row * T + kb + c);
      }
    }
    __syncthreads();

    const bool diag = (kt == qt);
    const int mtmax = diag ? (wid + 1) : 4;

    floatx16 S[4];
#pragma unroll
    for (int mt = 0; mt < 4; ++mt)
      if (mt < mtmax)
#pragma unroll
        for (int i = 0; i < 16; ++i) S[mt][i] = 0.f;

#pragma unroll
    for (int s = 0; s < 4; ++s) {
#pragma unroll
      for (int mt = 0; mt < 4; ++mt)
        if (mt < mtmax) {
          const short8 kf =
              *(const short8*)&Ks[(mt * 32 + l32) * 72 + s * 16 + hf * 8];
          S[mt] = __builtin_amdgcn_mfma_f32_32x32x16_bf16(kf, qf[s], S[mt], 0, 0, 0);
        }
    }

    if (diag) {
#pragma unroll
      for (int mt = 0; mt < 4; ++mt)
        if (mt == wid) {
#pragma unroll
          for (int r = 0; r < 16; ++r) {
            const int intra = (r & 3) + 8 * (r >> 2) + 4 * hf;
            if (intra > l32) S[mt][r] = -1e30f;
          }
        }
    }

    float tmax = -1e30f;
#pragma unroll
    for (int mt = 0; mt < 4; ++mt)
      if (mt < mtmax)
#pragma unroll
        for (int r = 0; r < 16; ++r) tmax = fmaxf(tmax, S[mt][r]);
    tmax = fmaxf(tmax, __shfl_xor(tmax, 32, 64));
    const float mn = fmaxf(mrun, tmax);
    const float alpha = __expf(mrun - mn);
    mrun = mn;

    float tsum = 0.f;
    uint32_t pk[4][8];
#pragma unroll
    for (int mt = 0; mt < 4; ++mt)
      if (mt < mtmax)
#pragma unroll
        for (int t = 0; t < 8; ++t) {
          const float pa = __expf(S[mt][2 * t] - mn);
          const float pb = __expf(S[mt][2 * t + 1] - mn);
          tsum += pa + pb;
          union { fp16x2 h; uint32_t u; } cv;
          cv.h = __builtin_amdgcn_cvt_pkrtz(pa, pb);
          pk[mt][t] = cv.u;
        }
    tsum += __shfl_xor(tsum, 32, 64);
    lrun = lrun * alpha + tsum;
#pragma unroll
    for (int mt2 = 0; mt2 < 2; ++mt2)
#pragma unroll
      for (int i = 0; i < 16; ++i) Oacc[mt2][i] *= alpha;

    const int smax = 2 * mtmax;
#pragma unroll
    for (int s = 0; s < 8; ++s)
      if (s < smax) {
        const int mt = s >> 1;
        const int bo = 4 * (s & 1);
        const uint32_t own0 = hf ? pk[mt][bo + 2] : pk[mt][bo];
        const uint32_t own1 = hf ? pk[mt][bo + 3] : pk[mt][bo + 1];
        const uint32_t sendA = hf ? pk[mt][bo] : pk[mt][bo + 2];
        const uint32_t sendB = hf ? pk[mt][bo + 1] : pk[mt][bo + 3];
        const uint32_t recvA = (uint32_t)__shfl_xor((int)sendA, 32, 64);
        const uint32_t recvB = (uint32_t)__shfl_xor((int)sendB, 32, 64);
        union { uint32_t u[4]; half8 h; } bb;
        bb.u[0] = hf ? recvA : own0;
        bb.u[1] = hf ? recvB : own1;
        bb.u[2] = hf ? own0 : recvA;
        bb.u[3] = hf ? own1 : recvB;
#pragma unroll
        for (int mt2 = 0; mt2 < 2; ++mt2) {
          const half8 vf =
              *(const half8*)&Vs[(mt2 * 32 + l32) * 136 + s * 16 + hf * 8];
          Oacc[mt2] = __builtin_amdgcn_mfma_f32_32x32x16_f16(vf, bb.h, Oacc[mt2], 0, 0, 0);
        }
      }
  }

  const float invl = 1.0f / lrun;
  const int b_ = bh >> 4, h_ = bh & 15;
  unsigned short* yrow = yws + ((size_t)(b_ * 2048 + q)) * 1024 + h_ * 64;
#pragma unroll
  for (int mt2 = 0; mt2 < 2; ++mt2)
#pragma unroll
    for (int t = 0; t < 8; ++t) {
      const int d0 = mt2 * 32 + 2 * (t & 1) + 8 * (t >> 1) + 4 * hf;
      const uint32_t ua = f2bf(Oacc[mt2][2 * t] * invl);
      const uint32_t ub = f2bf(Oacc[mt2][2 * t + 1] * invl);
      *(uint32_t*)&yrow[d0] = ua | (ub << 16);
    }
}

// ---------------------------------------------------------------------------
extern "C" void kernel_launch(void* const* d_in, const int* in_sizes, int n_in,
                              void* d_out, int out_size, void* d_ws, size_t ws_size,
                              hipStream_t stream) {
  (void)in_sizes; (void)n_in; (void)out_size;
  const float* x = (const float*)d_in[0];
  const float* attn_w = (const float*)d_in[1];
  const float* attn_b = (const float*)d_in[2];
  const float* proj_w = (const float*)d_in[3];
  const float* proj_b = (const float*)d_in[4];
  float* out = (float*)d_out;

  const size_t NQ = 8388608;  // 4*16*2048*64 == 8192*1024
  unsigned short* qws = (unsigned short*)d_ws;
  unsigned short* kws = qws + NQ;
  unsigned short* vws = kws + NQ;
  unsigned short* yws = vws + NQ;
  unsigned short* xb  = yws + NQ;
  unsigned short* wta = xb + NQ;               // 3072*1024
  unsigned short* wtp = wta + 3072 * 1024;     // 1024*1024
  if (ws_size < (5 * NQ + 4 * 1024 * 1024) * sizeof(unsigned short)) return;

  cvt_x_kernel<<<dim3(8192), dim3(256), 0, stream>>>(x, xb);
  transpose_w_kernel<<<dim3(48, 16), dim3(256), 0, stream>>>(attn_w, wta, 1024, 3072);
  transpose_w_kernel<<<dim3(16, 16), dim3(256), 0, stream>>>(proj_w, wtp, 1024, 1024);

  // QKV: M=8192, N=3072 (BN=256) -> 32x12 = 384 blocks.
  gemm256_kernel<0, 256><<<dim3(384), dim3(512), 0, stream>>>(
      xb, wta, attn_b, 8192, 3072, 1024, 12, qws, kws, vws, nullptr);
  attn_mfma_kernel<<<dim3(64, 16), dim3(256), 0, stream>>>(qws, kws, vws, yws);
  // Proj: M=8192, N=1024 (BN=128) -> 32x8 = 256 blocks (96KB LDS).
  gemm256_kernel<1, 128><<<dim3(256), dim3(512), 0, stream>>>(
      yws, wtp, proj_b, 8192, 1024, 1024, 8, nullptr, nullptr, nullptr, out);
}

// Round 8
// 276.435 us; speedup vs baseline: 3.0161x; 1.0103x over previous
//
#include <hip/hip_runtime.h>
#include <hip/hip_bf16.h>
#include <stdint.h>

#define DEV __device__ __forceinline__

typedef __attribute__((ext_vector_type(8))) short short8;
typedef __attribute__((ext_vector_type(8))) _Float16 half8;
typedef __attribute__((ext_vector_type(2))) __fp16 fp16x2;
typedef __attribute__((ext_vector_type(4))) float floatx4;
typedef __attribute__((ext_vector_type(16))) float floatx16;

DEV unsigned short f2bf(float f) {
  union { float f; uint32_t u; } v; v.f = f;
  uint32_t u = v.u;
  u += 0x7fffu + ((u >> 16) & 1u);   // RNE
  return (unsigned short)(u >> 16);
}
DEV unsigned short f2h(float f) {
  union { _Float16 h; unsigned short u; } c; c.h = (_Float16)f; return c.u;
}
DEV void async_cp16(const unsigned short* g, unsigned short* l) {
  __builtin_amdgcn_global_load_lds(
      (const __attribute__((address_space(1))) uint32_t*)g,
      (__attribute__((address_space(3))) uint32_t*)l, 16, 0, 0);
}

// ---------------------------------------------------------------------------
// cvt_x: fp32 -> bf16, coalesced. n multiple of 1024.
// ---------------------------------------------------------------------------
__global__ __launch_bounds__(256)
void cvt_x_kernel(const float* __restrict__ x, unsigned short* __restrict__ xb) {
  const size_t i = ((size_t)blockIdx.x * 256 + threadIdx.x) * 4;
  const float4 f = *(const float4*)(x + i);
  ushort4 w;
  w.x = f2bf(f.x); w.y = f2bf(f.y); w.z = f2bf(f.z); w.w = f2bf(f.w);
  *(ushort4*)(xb + i) = w;
}

// ---------------------------------------------------------------------------
// transpose_w: W[K][N] fp32 -> Wt[N][K] bf16. 64x64 LDS tiles.
// ---------------------------------------------------------------------------
__global__ __launch_bounds__(256)
void transpose_w_kernel(const float* __restrict__ W, unsigned short* __restrict__ Wt,
                        int K, int N) {
  __shared__ float tile[64][65];
  const int k0 = blockIdx.y * 64, n0 = blockIdx.x * 64;
  const int tr = threadIdx.x >> 4;
  const int tc = (threadIdx.x & 15) * 4;
#pragma unroll
  for (int it = 0; it < 4; ++it) {
    const int k = tr + it * 16;
    const float4 f = *(const float4*)(W + (size_t)(k0 + k) * N + n0 + tc);
    tile[k][tc + 0] = f.x; tile[k][tc + 1] = f.y;
    tile[k][tc + 2] = f.z; tile[k][tc + 3] = f.w;
  }
  __syncthreads();
#pragma unroll
  for (int it = 0; it < 4; ++it) {
    const int n = tr + it * 16;
    ushort4 w;
    w.x = f2bf(tile[tc + 0][n]); w.y = f2bf(tile[tc + 1][n]);
    w.z = f2bf(tile[tc + 2][n]); w.w = f2bf(tile[tc + 3][n]);
    *(ushort4*)(Wt + (size_t)(n0 + n) * K + k0 + tc) = w;
  }
}

// ---------------------------------------------------------------------------
// 256xBN 8-phase bf16 GEMM (r5-exact: best measured config, locally converged
// at ~100us / 515 TF across 6 structural variants). BK=64, 16 K-tiles.
// ---------------------------------------------------------------------------
#define BAR asm volatile("s_barrier" ::: "memory")
#define LGK0 asm volatile("s_waitcnt lgkmcnt(0)" ::: "memory")
#define VMW(N) asm volatile("s_waitcnt vmcnt(" #N ")" ::: "memory")
#define NOW (void)0
#define NOSTG (void)0

template <int EPI, int BN>
__global__ __launch_bounds__(512, 2)
void gemm256_kernel(const unsigned short* __restrict__ A,
                    const unsigned short* __restrict__ Bt,
                    const float* __restrict__ bias, int M, int N, int K,
                    int nbx,
                    unsigned short* __restrict__ qws,
                    unsigned short* __restrict__ kws,
                    unsigned short* __restrict__ vws,
                    float* __restrict__ out) {
  (void)M;
  constexpr int NF = BN / 64;  // per-wave n-frags; B rows = BN
  __shared__ __align__(16) unsigned short L[2][16384 + NF * 4096];
  const int tid = threadIdx.x;
  const int wid = tid >> 6, lane = tid & 63;
  const int quad = lane >> 4, l16 = lane & 15;
  const int wm = wid >> 2, wn = wid & 3;

  const int nwg = (int)gridDim.x;
  const int bid = (int)blockIdx.x;
  const int swz = (bid & 7) * (nwg >> 3) + (bid >> 3);
  const int bx = swz % nbx, by = swz / nbx;
  const int rowA0 = by * 256, colB0 = bx * BN;

  const int srow = tid >> 3;                              // 0..63
  const int ksrc = (((tid & 7) ^ (srow & 7)) << 3);       // shorts
  const unsigned short* pA00 = A + (size_t)(rowA0 + 0   + srow) * K + ksrc;
  const unsigned short* pA01 = A + (size_t)(rowA0 + 64  + srow) * K + ksrc;
  const unsigned short* pA10 = A + (size_t)(rowA0 + 128 + srow) * K + ksrc;
  const unsigned short* pA11 = A + (size_t)(rowA0 + 192 + srow) * K + ksrc;
  const unsigned short* pB00 = Bt + (size_t)(colB0 + 0   + srow) * K + ksrc;
  const unsigned short* pB01 = Bt + (size_t)(colB0 + 64  + srow) * K + ksrc;
  const unsigned short* pB10 =
      (BN == 256) ? Bt + (size_t)(colB0 + 128 + srow) * K + ksrc : pB00;
  const unsigned short* pB11 =
      (BN == 256) ? Bt + (size_t)(colB0 + 192 + srow) * K + ksrc : pB00;

#define STG_A0(P, T) do { async_cp16(pA00 + (T)*64, &L[P][0     + wid*512]); \
                          async_cp16(pA01 + (T)*64, &L[P][4096  + wid*512]); } while (0)
#define STG_A1(P, T) do { async_cp16(pA10 + (T)*64, &L[P][8192  + wid*512]); \
                          async_cp16(pA11 + (T)*64, &L[P][12288 + wid*512]); } while (0)
#define STG_B(P, T) do { \
    async_cp16(pB00 + (T)*64, &L[P][16384 + wid*512]); \
    async_cp16(pB01 + (T)*64, &L[P][20480 + wid*512]); \
    if constexpr (BN == 256) { \
      async_cp16(pB10 + (T)*64, &L[P][24576 + wid*512]); \
      async_cp16(pB11 + (T)*64, &L[P][28672 + wid*512]); } } while (0)
#define VMW_STEADY do { if constexpr (BN == 256) { VMW(4); } else { VMW(2); } } while (0)

  floatx4 acc[8][NF];
#pragma unroll
  for (int i = 0; i < 8; ++i)
#pragma unroll
    for (int j = 0; j < NF; ++j) acc[i][j] = (floatx4){0.f, 0.f, 0.f, 0.f};
  short8 bfrag[NF];

  STG_A0(0, 0); STG_A1(0, 0); STG_B(0, 0);
  STG_B(1, 1);
  VMW_STEADY;
  BAR;

#define PHASE(PAR, QM, RB, STG, W)                                            \
  {                                                                           \
    short8 a_[4];                                                             \
    _Pragma("unroll") for (int m_ = 0; m_ < 4; ++m_) {                        \
      const int row_ = wm * 128 + ((QM)*4 + m_) * 16 + l16;                   \
      a_[m_] = *(const short8*)&L[PAR][row_ * 64 +                            \
                 (((0) + quad * 8) ^ ((row_ & 7) << 3))];                     \
    }                                                                         \
    (void)0;                                                                  \
    if (RB) {                                                                 \
      _Pragma("unroll") for (int n_ = 0; n_ < NF; ++n_) {                     \
        const int row_ = wn * (BN / 4) + n_ * 16 + l16;                       \
        bfrag[n_] = *(const short8*)&L[PAR][16384 + row_ * 64 +               \
                 (((0) + quad * 8) ^ ((row_ & 7) << 3))];                     \
      }                                                                       \
    }                                                                         \
    STG;                                                                      \
    BAR;                                                                      \
    LGK0;                                                                     \
    __builtin_amdgcn_s_setprio(1);                                            \
    _Pragma("unroll") for (int m_ = 0; m_ < 4; ++m_)                          \
      _Pragma("unroll") for (int n_ = 0; n_ < NF; ++n_)                       \
        acc[(QM)*4 + m_][n_] = __builtin_amdgcn_mfma_f32_16x16x32_bf16(       \
            a_[m_], bfrag[n_], acc[(QM)*4 + m_][n_], 0, 0, 0);                \
    __builtin_amdgcn_s_setprio(0);                                            \
    W;                                                                        \
    BAR;                                                                      \
  }

// Phases read K-halves via KS in the byte offset; regenerate with KS folded.
#undef PHASE
#define PHASE(PAR, QM, KS, RB, STG, W)                                        \
  {                                                                           \
    short8 a_[4];                                                             \
    _Pragma("unroll") for (int m_ = 0; m_ < 4; ++m_) {                        \
      const int row_ = wm * 128 + ((QM)*4 + m_) * 16 + l16;                   \
      a_[m_] = *(const short8*)&L[PAR][row_ * 64 +                            \
                 ((((KS)*32) + quad * 8) ^ ((row_ & 7) << 3))];               \
    }                                                                         \
    if (RB) {                                                                 \
      _Pragma("unroll") for (int n_ = 0; n_ < NF; ++n_) {                     \
        const int row_ = wn * (BN / 4) + n_ * 16 + l16;                       \
        bfrag[n_] = *(const short8*)&L[PAR][16384 + row_ * 64 +               \
                 ((((KS)*32) + quad * 8) ^ ((row_ & 7) << 3))];               \
      }                                                                       \
    }                                                                         \
    STG;                                                                      \
    BAR;                                                                      \
    LGK0;                                                                     \
    __builtin_amdgcn_s_setprio(1);                                            \
    _Pragma("unroll") for (int m_ = 0; m_ < 4; ++m_)                          \
      _Pragma("unroll") for (int n_ = 0; n_ < NF; ++n_)                       \
        acc[(QM)*4 + m_][n_] = __builtin_amdgcn_mfma_f32_16x16x32_bf16(       \
            a_[m_], bfrag[n_], acc[(QM)*4 + m_][n_], 0, 0, 0);                \
    __builtin_amdgcn_s_setprio(0);                                            \
    W;                                                                        \
    BAR;                                                                      \
  }

#define KTILE(PAR, S1, S2, S4, W4) \
  PHASE(PAR, 0, 0, 1, S1, NOW)     \
  PHASE(PAR, 1, 0, 0, S2, NOW)     \
  PHASE(PAR, 0, 1, 1, NOSTG, NOW)  \
  PHASE(PAR, 1, 1, 0, S4, W4)

  for (int t0 = 0; t0 < 14; t0 += 2) {
    KTILE(0, STG_A0(1, t0 + 1), STG_A1(1, t0 + 1), STG_B(0, t0 + 2), VMW_STEADY)
    KTILE(1, STG_A0(0, t0 + 2), STG_A1(0, t0 + 2), STG_B(1, t0 + 3), VMW_STEADY)
  }
  KTILE(0, STG_A0(1, 15), STG_A1(1, 15), NOSTG, VMW(0))
  KTILE(1, NOSTG, NOSTG, NOSTG, NOW)

#undef KTILE
#undef PHASE
#undef STG_A0
#undef STG_A1
#undef STG_B
#undef VMW_STEADY

  // Epilogue. C/D: row = quad*4 + r, col = l16.
#pragma unroll
  for (int mi = 0; mi < 8; ++mi) {
#pragma unroll
    for (int ni = 0; ni < NF; ++ni) {
      const int row0 = rowA0 + wm * 128 + mi * 16 + quad * 4;
      const int col = colB0 + wn * (BN / 4) + ni * 16 + l16;
      const float bv = bias[col];
#pragma unroll
      for (int r = 0; r < 4; ++r) {
        const float v = acc[mi][ni][r] + bv;
        const int R = row0 + r;
        if constexpr (EPI == 0) {
          const int b = R >> 11, t = R & 2047;
          const int which = col >> 10, c = col & 1023;
          const int h = c >> 6, dd = c & 63;
          const size_t bh = (size_t)(b * 16 + h);
          if (which == 0)
            qws[(bh * 2048 + t) * 64 + dd] = f2bf(v * 0.125f);  // Q, scale folded
          else if (which == 1)
            kws[(bh * 2048 + t) * 64 + dd] = f2bf(v);           // K [bh][t][d]
          else
            vws[(bh * 64 + dd) * 2048 + t] = f2h(v);            // V^T f16 [bh][d][t]
        } else {
          out[(size_t)R * N + col] = v;
        }
      }
    }
  }
}

// ---------------------------------------------------------------------------
// MFMA flash attention with T14 async-STAGE (load-early / write-late).
// Grid (64 bh, 16 qtiles), block 256 = 4 waves.
// Old: __syncthreads -> reg loads -> LDS writes -> __syncthreads -> compute.
// __syncthreads drains vmcnt(0), so tile t+1's global loads serialized
// against compute(t). Now: raw s_barrier; issue loads(t+1) AFTER writing
// tile t to LDS, so they fly during compute(t); lgkmcnt(0) before the
// second barrier makes ds_writes visible. Layout/pitches unchanged.
// ---------------------------------------------------------------------------
__global__ __launch_bounds__(256, 2)
void attn_mfma_kernel(const unsigned short* __restrict__ qws,
                      const unsigned short* __restrict__ kws,
                      const unsigned short* __restrict__ vws,
                      unsigned short* __restrict__ yws) {
  constexpr int T = 2048, D = 64;
  __shared__ __align__(16) unsigned short Ks[128 * 72];
  __shared__ __align__(16) unsigned short Vs[64 * 136];
  const int tid = threadIdx.x;
  const int wid = tid >> 6, lane = tid & 63;
  const int hf = lane >> 5, l32 = lane & 31;
  const int bh = blockIdx.x;
  const int qt = 15 - (int)blockIdx.y;
  const int qbase = qt * 128;
  const unsigned short* Qp = qws + (size_t)bh * T * D;
  const unsigned short* Kp = kws + (size_t)bh * T * D;
  const unsigned short* Vp = vws + (size_t)bh * D * T;

  const int q = qbase + wid * 32 + l32;
  short8 qf[4];
#pragma unroll
  for (int s = 0; s < 4; ++s)
    qf[s] = *(const short8*)(Qp + (size_t)q * D + s * 16 + hf * 8);

  floatx16 Oacc[2];
#pragma unroll
  for (int mt2 = 0; mt2 < 2; ++mt2)
#pragma unroll
    for (int i = 0; i < 16; ++i) Oacc[mt2][i] = 0.f;
  float mrun = -1e30f, lrun = 0.f;

  // T14 staging state: this thread's K/V 16B chunks of the CURRENT tile.
  const int krow0 = tid >> 3, kc = (tid & 7) * 8;    // K: 128 rows x 8 chunks
  const int vrow0 = tid >> 4, vc = (tid & 15) * 8;   // V: 64 rows x 16 chunks
  short8 kreg[4], vreg[4];
#define ALOAD(KB) do { _Pragma("unroll") for (int it_ = 0; it_ < 4; ++it_) { \
    kreg[it_] = *(const short8*)(Kp + (size_t)((KB) + krow0 + it_ * 32) * D + kc); \
    vreg[it_] = *(const short8*)(Vp + (size_t)(vrow0 + it_ * 16) * T + (KB) + vc); \
  } } while (0)

  ALOAD(0);

  for (int kt = 0; kt <= qt; ++kt) {
    BAR;  // all waves finished reading the previous tile's LDS
    // write current tile (compiler inserts the vmcnt wait for kreg/vreg)
#pragma unroll
    for (int it_ = 0; it_ < 4; ++it_) {
      *(short8*)&Ks[(krow0 + it_ * 32) * 72 + kc] = kreg[it_];
      *(short8*)&Vs[(vrow0 + it_ * 16) * 136 + vc] = vreg[it_];
    }
    if (kt < qt) ALOAD((kt + 1) * 128);  // fly during compute below
    LGK0;  // ds_writes visible before signaling
    BAR;   // LDS ready

    const bool diag = (kt == qt);
    const int mtmax = diag ? (wid + 1) : 4;

    floatx16 S[4];
#pragma unroll
    for (int mt = 0; mt < 4; ++mt)
      if (mt < mtmax)
#pragma unroll
        for (int i = 0; i < 16; ++i) S[mt][i] = 0.f;

#pragma unroll
    for (int s = 0; s < 4; ++s) {
#pragma unroll
      for (int mt = 0; mt < 4; ++mt)
        if (mt < mtmax) {
          const short8 kf =
              *(const short8*)&Ks[(mt * 32 + l32) * 72 + s * 16 + hf * 8];
          S[mt] = __builtin_amdgcn_mfma_f32_32x32x16_bf16(kf, qf[s], S[mt], 0, 0, 0);
        }
    }

    if (diag) {
#pragma unroll
      for (int mt = 0; mt < 4; ++mt)
        if (mt == wid) {
#pragma unroll
          for (int r = 0; r < 16; ++r) {
            const int intra = (r & 3) + 8 * (r >> 2) + 4 * hf;
            if (intra > l32) S[mt][r] = -1e30f;
          }
        }
    }

    float tmax = -1e30f;
#pragma unroll
    for (int mt = 0; mt < 4; ++mt)
      if (mt < mtmax)
#pragma unroll
        for (int r = 0; r < 16; ++r) tmax = fmaxf(tmax, S[mt][r]);
    tmax = fmaxf(tmax, __shfl_xor(tmax, 32, 64));
    const float mn = fmaxf(mrun, tmax);
    const float alpha = __expf(mrun - mn);
    mrun = mn;

    float tsum = 0.f;
    uint32_t pk[4][8];
#pragma unroll
    for (int mt = 0; mt < 4; ++mt)
      if (mt < mtmax)
#pragma unroll
        for (int t = 0; t < 8; ++t) {
          const float pa = __expf(S[mt][2 * t] - mn);
          const float pb = __expf(S[mt][2 * t + 1] - mn);
          tsum += pa + pb;
          union { fp16x2 h; uint32_t u; } cv;
          cv.h = __builtin_amdgcn_cvt_pkrtz(pa, pb);
          pk[mt][t] = cv.u;
        }
    tsum += __shfl_xor(tsum, 32, 64);
    lrun = lrun * alpha + tsum;
#pragma unroll
    for (int mt2 = 0; mt2 < 2; ++mt2)
#pragma unroll
      for (int i = 0; i < 16; ++i) Oacc[mt2][i] *= alpha;

    const int smax = 2 * mtmax;
#pragma unroll
    for (int s = 0; s < 8; ++s)
      if (s < smax) {
        const int mt = s >> 1;
        const int bo = 4 * (s & 1);
        const uint32_t own0 = hf ? pk[mt][bo + 2] : pk[mt][bo];
        const uint32_t own1 = hf ? pk[mt][bo + 3] : pk[mt][bo + 1];
        const uint32_t sendA = hf ? pk[mt][bo] : pk[mt][bo + 2];
        const uint32_t sendB = hf ? pk[mt][bo + 1] : pk[mt][bo + 3];
        const uint32_t recvA = (uint32_t)__shfl_xor((int)sendA, 32, 64);
        const uint32_t recvB = (uint32_t)__shfl_xor((int)sendB, 32, 64);
        union { uint32_t u[4]; half8 h; } bb;
        bb.u[0] = hf ? recvA : own0;
        bb.u[1] = hf ? recvB : own1;
        bb.u[2] = hf ? own0 : recvA;
        bb.u[3] = hf ? own1 : recvB;
#pragma unroll
        for (int mt2 = 0; mt2 < 2; ++mt2) {
          const half8 vf =
              *(const half8*)&Vs[(mt2 * 32 + l32) * 136 + s * 16 + hf * 8];
          Oacc[mt2] = __builtin_amdgcn_mfma_f32_32x32x16_f16(vf, bb.h, Oacc[mt2], 0, 0, 0);
        }
      }
  }
#undef ALOAD

  const float invl = 1.0f / lrun;
  const int b_ = bh >> 4, h_ = bh & 15;
  unsigned short* yrow = yws + ((size_t)(b_ * 2048 + q)) * 1024 + h_ * 64;
#pragma unroll
  for (int mt2 = 0; mt2 < 2; ++mt2)
#pragma unroll
    for (int t = 0; t < 8; ++t) {
      const int d0 = mt2 * 32 + 2 * (t & 1) + 8 * (t >> 1) + 4 * hf;
      const uint32_t ua = f2bf(Oacc[mt2][2 * t] * invl);
      const uint32_t ub = f2bf(Oacc[mt2][2 * t + 1] * invl);
      *(uint32_t*)&yrow[d0] = ua | (ub << 16);
    }
}

// ---------------------------------------------------------------------------
extern "C" void kernel_launch(void* const* d_in, const int* in_sizes, int n_in,
                              void* d_out, int out_size, void* d_ws, size_t ws_size,
                              hipStream_t stream) {
  (void)in_sizes; (void)n_in; (void)out_size;
  const float* x = (const float*)d_in[0];
  const float* attn_w = (const float*)d_in[1];
  const float* attn_b = (const float*)d_in[2];
  const float* proj_w = (const float*)d_in[3];
  const float* proj_b = (const float*)d_in[4];
  float* out = (float*)d_out;

  const size_t NQ = 8388608;  // 4*16*2048*64 == 8192*1024
  unsigned short* qws = (unsigned short*)d_ws;
  unsigned short* kws = qws + NQ;
  unsigned short* vws = kws + NQ;
  unsigned short* yws = vws + NQ;
  unsigned short* xb  = yws + NQ;
  unsigned short* wta = xb + NQ;               // 3072*1024
  unsigned short* wtp = wta + 3072 * 1024;     // 1024*1024
  if (ws_size < (5 * NQ + 4 * 1024 * 1024) * sizeof(unsigned short)) return;

  cvt_x_kernel<<<dim3(8192), dim3(256), 0, stream>>>(x, xb);
  transpose_w_kernel<<<dim3(48, 16), dim3(256), 0, stream>>>(attn_w, wta, 1024, 3072);
  transpose_w_kernel<<<dim3(16, 16), dim3(256), 0, stream>>>(proj_w, wtp, 1024, 1024);

  // QKV: M=8192, N=3072 (BN=256) -> 32x12 = 384 blocks.
  gemm256_kernel<0, 256><<<dim3(384), dim3(512), 0, stream>>>(
      xb, wta, attn_b, 8192, 3072, 1024, 12, qws, kws, vws, nullptr);
  attn_mfma_kernel<<<dim3(64, 16), dim3(256), 0, stream>>>(qws, kws, vws, yws);
  // Proj: M=8192, N=1024 (BN=128) -> 32x8 = 256 blocks (48KB LDS).
  gemm256_kernel<1, 128><<<dim3(256), dim3(512), 0, stream>>>(
      yws, wtp, proj_b, 8192, 1024, 1024, 8, nullptr, nullptr, nullptr, out);
}